// Round 1
// baseline (209.539 us; speedup 1.0000x reference)
//
#include <hip/hip_runtime.h>

#define B_TOTAL 16384
#define F_DIM 512
#define H_DIM 256
#define E_NUM 8
#define OUT_COLS 32
#define DA 8
#define TM 64
#define HSTRIDE (H_DIM + 8)   // 264 halves: rows 16B-aligned, 528B stride

typedef __attribute__((ext_vector_type(8))) _Float16 half8;
typedef __attribute__((ext_vector_type(4))) _Float16 half4;
typedef __attribute__((ext_vector_type(4))) float float4v;

// ---------------- bucket samples by expert ----------------
__global__ void k_bucket(const int* __restrict__ act, int* __restrict__ counts,
                         int* __restrict__ idxbuf) {
  int b = blockIdx.x * 256 + threadIdx.x;
  if (b < B_TOTAL) {
    int e = act[b] & 7;
    int pos = atomicAdd(&counts[e], 1);
    idxbuf[e * B_TOTAL + pos] = b;
  }
}

// ---------------- transpose + fp32->fp16 convert: (E,K,N) -> (E,N,K) ----------------
template <int K, int N>
__global__ void k_transpose(const float* __restrict__ src, _Float16* __restrict__ dst) {
  __shared__ float tile[32][33];
  int e = blockIdx.z;
  const float* S = src + (size_t)e * K * N;
  _Float16* D = dst + (size_t)e * N * K;
  int k0 = blockIdx.x * 32, n0 = blockIdx.y * 32;
  int tx = threadIdx.x & 31, ty = threadIdx.x >> 5;  // 32x8
#pragma unroll
  for (int r = 0; r < 32; r += 8)
    tile[ty + r][tx] = S[(size_t)(k0 + ty + r) * N + (n0 + tx)];
  __syncthreads();
#pragma unroll
  for (int r = 0; r < 32; r += 8)
    D[(size_t)(n0 + ty + r) * K + (k0 + tx)] = (_Float16)tile[tx][ty + r];
}

// ---------------- W3: (E,256,32) -> (E,16,256) fp16, rows 8..15 zero ----------------
__global__ void k_w3prep(const float* __restrict__ W3, _Float16* __restrict__ W3t) {
  int e = blockIdx.x;
  int k = threadIdx.x;  // 0..255
#pragma unroll
  for (int o = 0; o < 16; ++o) {
    float v = (o < DA) ? W3[((size_t)e * H_DIM + k) * OUT_COLS + o] : 0.f;
    W3t[((size_t)e * 16 + o) * H_DIM + k] = (_Float16)v;
  }
}

// ---------------- fused 3-layer expert MLP ----------------
__global__ __launch_bounds__(256, 2) void k_mlp(
    const float* __restrict__ X,
    const _Float16* __restrict__ W1t,
    const _Float16* __restrict__ W2t,
    const _Float16* __restrict__ W3t,
    const float* __restrict__ b1,
    const float* __restrict__ b2,
    const float* __restrict__ b3,
    const int* __restrict__ counts,
    const int* __restrict__ idxbuf,
    float* __restrict__ out)
{
  int e = blockIdx.y;
  int cnt = counts[e];
  int tile0 = blockIdx.x * TM;
  if (tile0 >= cnt) return;

  __shared__ _Float16 H1s[TM][HSTRIDE];
  __shared__ _Float16 H2s[TM][HSTRIDE];
  __shared__ float bias1[H_DIM];
  __shared__ float bias2[H_DIM];
  __shared__ float bias3[16];

  int t = threadIdx.x;
  bias1[t] = b1[e * H_DIM + t];
  bias2[t] = b2[e * H_DIM + t];
  if (t < 16) bias3[t] = (t < DA) ? b3[e * OUT_COLS + t] : 0.f;

  int lane = t & 63;
  int wave = t >> 6;   // 0..3: owns hidden rows [wave*64, wave*64+64)
  int quad = lane >> 4;
  int l16 = lane & 15;

  // gathered feature rows for the 4 sample sub-tiles (B-fragment n-index = l16)
  const float* xrow[4];
#pragma unroll
  for (int st = 0; st < 4; ++st) {
    int si = tile0 + st * 16 + l16;
    int row = (si < cnt) ? idxbuf[e * B_TOTAL + si] : 0;
    xrow[st] = X + (size_t)row * F_DIM;
  }
  __syncthreads();  // biases staged

  float4v acc[4][4];
  const float4v vzero = {0.f, 0.f, 0.f, 0.f};
#pragma unroll
  for (int mt = 0; mt < 4; ++mt)
#pragma unroll
    for (int st = 0; st < 4; ++st) acc[mt][st] = vzero;

  int hbase = wave * 64;
  int kq = quad * 8;

  // ======== Layer 1: H1^T[h][s] = sum_k W1t[h][k] * X[s][k] ========
  {
    const _Float16* wbase = W1t + ((size_t)e * H_DIM + hbase + l16) * F_DIM;
    for (int kb = 0; kb < F_DIM; kb += 32) {
      int kofs = kb + kq;
      half8 bfrag[4];
#pragma unroll
      for (int st = 0; st < 4; ++st) {
        const float* p = xrow[st] + kofs;
        float4v x0 = *(const float4v*)p;
        float4v x1 = *(const float4v*)(p + 4);
        half8 h;
        h[0] = (_Float16)x0.x; h[1] = (_Float16)x0.y;
        h[2] = (_Float16)x0.z; h[3] = (_Float16)x0.w;
        h[4] = (_Float16)x1.x; h[5] = (_Float16)x1.y;
        h[6] = (_Float16)x1.z; h[7] = (_Float16)x1.w;
        bfrag[st] = h;
      }
#pragma unroll
      for (int mt = 0; mt < 4; ++mt) {
        half8 afrag = *(const half8*)(wbase + (size_t)mt * 16 * F_DIM + kofs);
#pragma unroll
        for (int st = 0; st < 4; ++st)
          acc[mt][st] = __builtin_amdgcn_mfma_f32_16x16x32_f16(afrag, bfrag[st], acc[mt][st], 0, 0, 0);
      }
    }
    // epilogue: bias + relu -> H1s[sample][hidden] (C row=quad*4+r -> hidden, col=l16 -> sample)
#pragma unroll
    for (int mt = 0; mt < 4; ++mt) {
      int h0 = hbase + mt * 16 + quad * 4;
      float4v bb = *(const float4v*)&bias1[h0];
#pragma unroll
      for (int st = 0; st < 4; ++st) {
        int s = st * 16 + l16;
        half4 hv;
#pragma unroll
        for (int r = 0; r < 4; ++r) {
          float v = acc[mt][st][r] + bb[r];
          hv[r] = (_Float16)(v > 0.f ? v : 0.f);
        }
        *(half4*)&H1s[s][h0] = hv;
      }
    }
  }
  __syncthreads();

  // ======== Layer 2: H2^T[h][s] = sum_k W2t[h][k] * H1[s][k] ========
#pragma unroll
  for (int mt = 0; mt < 4; ++mt)
#pragma unroll
    for (int st = 0; st < 4; ++st) acc[mt][st] = vzero;
  {
    const _Float16* wbase = W2t + ((size_t)e * H_DIM + hbase + l16) * H_DIM;
    for (int kb = 0; kb < H_DIM; kb += 32) {
      int kofs = kb + kq;
      half8 bfrag[4];
#pragma unroll
      for (int st = 0; st < 4; ++st)
        bfrag[st] = *(const half8*)&H1s[st * 16 + l16][kofs];
#pragma unroll
      for (int mt = 0; mt < 4; ++mt) {
        half8 afrag = *(const half8*)(wbase + (size_t)mt * 16 * H_DIM + kofs);
#pragma unroll
        for (int st = 0; st < 4; ++st)
          acc[mt][st] = __builtin_amdgcn_mfma_f32_16x16x32_f16(afrag, bfrag[st], acc[mt][st], 0, 0, 0);
      }
    }
#pragma unroll
    for (int mt = 0; mt < 4; ++mt) {
      int h0 = hbase + mt * 16 + quad * 4;
      float4v bb = *(const float4v*)&bias2[h0];
#pragma unroll
      for (int st = 0; st < 4; ++st) {
        int s = st * 16 + l16;
        half4 hv;
#pragma unroll
        for (int r = 0; r < 4; ++r) {
          float v = acc[mt][st][r] + bb[r];
          hv[r] = (_Float16)(v > 0.f ? v : 0.f);
        }
        *(half4*)&H2s[s][h0] = hv;
      }
    }
  }
  __syncthreads();

  // ======== Layer 3: Y^T[o][s] = sum_k W3t[o][k] * H2[s][k]; wave handles sample tile = wave ========
  {
    float4v acc3 = vzero;
    const _Float16* wbase = W3t + ((size_t)e * 16 + l16) * H_DIM;
    for (int kb = 0; kb < H_DIM; kb += 32) {
      int kofs = kb + kq;
      half8 afrag = *(const half8*)(wbase + kofs);
      half8 bfrag = *(const half8*)&H2s[wave * 16 + l16][kofs];
      acc3 = __builtin_amdgcn_mfma_f32_16x16x32_f16(afrag, bfrag, acc3, 0, 0, 0);
    }
    int si = tile0 + wave * 16 + l16;
    if (quad < 2 && si < cnt) {
      int row = idxbuf[e * B_TOTAL + si];
      float4v y;
#pragma unroll
      for (int r = 0; r < 4; ++r) y[r] = acc3[r] + bias3[quad * 4 + r];
      *(float4v*)&out[(size_t)row * DA + quad * 4] = y;
    }
  }
}

extern "C" void kernel_launch(void* const* d_in, const int* in_sizes, int n_in,
                              void* d_out, int out_size, void* d_ws, size_t ws_size,
                              hipStream_t stream) {
  const float* features = (const float*)d_in[0];
  const float* W1 = (const float*)d_in[1];
  const float* b1 = (const float*)d_in[2];
  const float* W2 = (const float*)d_in[3];
  const float* b2 = (const float*)d_in[4];
  const float* W3 = (const float*)d_in[5];
  const float* b3 = (const float*)d_in[6];
  const int* act = (const int*)d_in[7];
  float* out = (float*)d_out;

  char* ws = (char*)d_ws;
  int* counts = (int*)ws;                                   // 256 B
  int* idxbuf = (int*)(ws + 256);                           // 8*16384*4 = 512 KiB
  _Float16* W1t = (_Float16*)(ws + 256 + 524288);           // 2 MiB
  _Float16* W2t = (_Float16*)(ws + 256 + 524288 + 2097152); // 1 MiB
  _Float16* W3t = (_Float16*)(ws + 256 + 524288 + 2097152 + 1048576); // 64 KiB

  hipMemsetAsync(counts, 0, 256, stream);
  k_bucket<<<B_TOTAL / 256, 256, 0, stream>>>(act, counts, idxbuf);
  k_transpose<F_DIM, H_DIM><<<dim3(F_DIM / 32, H_DIM / 32, E_NUM), 256, 0, stream>>>(W1, W1t);
  k_transpose<H_DIM, H_DIM><<<dim3(H_DIM / 32, H_DIM / 32, E_NUM), 256, 0, stream>>>(W2, W2t);
  k_w3prep<<<E_NUM, H_DIM, 0, stream>>>(W3, W3t);
  k_mlp<<<dim3(B_TOTAL / TM, E_NUM), 256, 0, stream>>>(features, W1t, W2t, W3t,
                                                       b1, b2, b3, counts, idxbuf, out);
}